// Round 1
// baseline (624.243 us; speedup 1.0000x reference)
//
#include <hip/hip_runtime.h>
#include <stdint.h>

#define N 2048
#define TILE 128
#define BK 64
#define KI (N / BK)      // 32 K-steps
#define LDSW 72          // u16 row stride: 144 B rows -> 16B-aligned b128, conflict-free
#define RW 33            // padded f32 row stride for the pair-exchange epilogue
#define NN ((size_t)N * (size_t)N)

typedef unsigned short u16;
typedef __bf16 bf16x8 __attribute__((ext_vector_type(8)));
typedef unsigned short ushortx8 __attribute__((ext_vector_type(8)));
typedef float floatx4 __attribute__((ext_vector_type(4)));

// LDS: main-loop staging buffers alias the epilogue exchange buffer.
union Smem {
  u16 ab[2][2][TILE * LDSW];  // [A|B][buf][row*LDSW + col]   73,728 B
  float red[4][2][64 * RW];   // [pair][half][row*RW + col]   67,584 B
};
static_assert(sizeof(Smem) <= 160 * 1024, "LDS overflow");

static __device__ __forceinline__ u16 f2bf(float f) {
  unsigned int u = __builtin_bit_cast(unsigned int, f);
  return (u16)((u + 0x7fffu + ((u >> 16) & 1u)) >> 16);  // RNE, finite inputs
}

// XCD-region swizzle: 256 blocks round-robin over 8 XCDs (bid&7); give each
// XCD a fixed 4x8 region of the 16x16 tile grid so its L2 holds ~6 MB of
// A/B panels instead of ~9 MB. Bijective since 256 % 8 == 0.
static __device__ __forceinline__ void tile_xy(int bid, int& bx, int& by) {
  const int xcd = bid & 7, j = bid >> 3;   // j in [0,32)
  bx = (xcd & 3) * 4 + (j & 3);
  by = (xcd >> 2) * 8 + (j >> 2);
}

// ---------------------------------------------------------------------------
// cast + transpose: Ab[r][c] = bf16(A[r][c]); Abt[c][r] = bf16(A[r][c]);
// block (0,0) also zeroes the fused-rowsum accumulator.
// ---------------------------------------------------------------------------
__global__ void cast_tr(const float* __restrict__ A, u16* __restrict__ Ab,
                        u16* __restrict__ Abt, float* __restrict__ rsum) {
  __shared__ float tile[32][33];
  const int tx = threadIdx.x, ty = threadIdx.y;
  if (blockIdx.x == 0 && blockIdx.y == 0) {
    const int tid = ty * 32 + tx;
    for (int k = tid; k < N; k += 256) rsum[k] = 0.f;
  }
  const int c = blockIdx.x * 32 + tx;
#pragma unroll
  for (int i = 0; i < 4; i++) {
    const int r = blockIdx.y * 32 + ty + i * 8;
    const float v = A[(size_t)r * N + c];
    Ab[(size_t)r * N + c] = f2bf(v);
    tile[ty + i * 8][tx] = v;
  }
  __syncthreads();
  const int r2 = blockIdx.y * 32 + tx;
#pragma unroll
  for (int i = 0; i < 4; i++) {
    const int c2 = blockIdx.x * 32 + ty + i * 8;
    Abt[(size_t)c2 * N + r2] = f2bf(tile[tx][ty + i * 8]);
  }
}

// ---------------------------------------------------------------------------
// GEMM core: C = L[128 x N] * R[N x 128] (Rt stored [n][k]).
// 512 threads = 8 waves. 4 wave-PAIRS each own a 64x64 output tile
// (pair = w&3 -> wr=(pair&1)*64, wc=(pair>>1)*64); the two waves of a pair
// split each BK=64 step's K range (ks = w>>2 takes k in [ks*32, ks*32+32)).
// -> 4x4 MFMAs per wave per step from 8 ds_read_b128 (512 B frag-read/MFMA
//    vs 768 for the old 64x32 tiles).
// Double-buffered LDS with ONE barrier per K-step: a wave's reads of
// buf[cur] are lgkm-drained before it arrives at barrier i, so writes to
// buf[cur^1] after barrier i can never race them. Register prefetch depth 2.
// ---------------------------------------------------------------------------
__device__ __forceinline__ void gemm_core(const u16* __restrict__ L,
                                          const u16* __restrict__ Rt,
                                          Smem& sm, int row0, int col0,
                                          floatx4 acc[4][4]) {
  const int t = threadIdx.x;  // 0..511
  // staging map: thread t covers row t>>2 (0..127), 32B chunk (t&3) of BK=64
  const int srow = t >> 2;
  const int sc = (t & 3) * 16;  // u16 offset, 32 B per thread per tile row
  const u16* gA = L + (size_t)(row0 + srow) * N + sc;
  const u16* gB = Rt + (size_t)(col0 + srow) * N + sc;
  const int woff = srow * LDSW + sc;

  const int lane = t & 63;
  const int w = t >> 6;
  const int pair = w & 3;
  const int half = w >> 2;  // K-half of each BK tile this wave handles
  const int wr = (pair & 1) * 64;
  const int wc = (pair >> 1) * 64;
  const int lr = lane & 15;
  const int q = lane >> 4;
  const int aoff = (wr + lr) * LDSW + half * 32 + q * 8;
  const int boff = (wc + lr) * LDSW + half * 32 + q * 8;

#pragma unroll
  for (int i = 0; i < 4; i++)
#pragma unroll
    for (int j = 0; j < 4; j++) acc[i][j] = (floatx4){0.f, 0.f, 0.f, 0.f};

  ushortx8 sA[2][2], sB[2][2];  // [slot = tile&1][16B chunk]
  // prologue: tiles 0 and 1 into registers; publish tile 0
  sA[0][0] = *(const ushortx8*)(gA);
  sA[0][1] = *(const ushortx8*)(gA + 8);
  sB[0][0] = *(const ushortx8*)(gB);
  sB[0][1] = *(const ushortx8*)(gB + 8);
  sA[1][0] = *(const ushortx8*)(gA + BK);
  sA[1][1] = *(const ushortx8*)(gA + BK + 8);
  sB[1][0] = *(const ushortx8*)(gB + BK);
  sB[1][1] = *(const ushortx8*)(gB + BK + 8);
  *(ushortx8*)&sm.ab[0][0][woff] = sA[0][0];
  *(ushortx8*)&sm.ab[0][0][woff + 8] = sA[0][1];
  *(ushortx8*)&sm.ab[1][0][woff] = sB[0][0];
  *(ushortx8*)&sm.ab[1][0][woff + 8] = sB[0][1];
  __syncthreads();

  // step i: read buf[cur]=tile i; issue loads tile i+2 -> slot[cur] (freed by
  // step i-1's publish); publish tile i+1 from slot[nxt] -> buf[nxt]; barrier.
#define GSTEP(i, cur, nxt)                                                    \
  {                                                                           \
    if ((i) + 2 < KI) {                                                       \
      sA[cur][0] = *(const ushortx8*)(gA + ((i) + 2) * BK);                   \
      sA[cur][1] = *(const ushortx8*)(gA + ((i) + 2) * BK + 8);               \
      sB[cur][0] = *(const ushortx8*)(gB + ((i) + 2) * BK);                   \
      sB[cur][1] = *(const ushortx8*)(gB + ((i) + 2) * BK + 8);               \
    }                                                                         \
    bf16x8 af[4], bfr[4];                                                     \
    _Pragma("unroll") for (int mt = 0; mt < 4; mt++) af[mt] =                 \
        __builtin_bit_cast(bf16x8,                                            \
            *(const ushortx8*)&sm.ab[0][cur][aoff + mt * 16 * LDSW]);         \
    _Pragma("unroll") for (int nt = 0; nt < 4; nt++) bfr[nt] =                \
        __builtin_bit_cast(bf16x8,                                            \
            *(const ushortx8*)&sm.ab[1][cur][boff + nt * 16 * LDSW]);         \
    _Pragma("unroll") for (int mt = 0; mt < 4; mt++)                          \
        _Pragma("unroll") for (int nt = 0; nt < 4; nt++) acc[mt][nt] =        \
            __builtin_amdgcn_mfma_f32_16x16x32_bf16(af[mt], bfr[nt],          \
                                                    acc[mt][nt], 0, 0, 0);    \
    if ((i) + 1 < KI) {                                                       \
      *(ushortx8*)&sm.ab[0][nxt][woff] = sA[nxt][0];                          \
      *(ushortx8*)&sm.ab[0][nxt][woff + 8] = sA[nxt][1];                      \
      *(ushortx8*)&sm.ab[1][nxt][woff] = sB[nxt][0];                          \
      *(ushortx8*)&sm.ab[1][nxt][woff + 8] = sB[nxt][1];                      \
    }                                                                         \
    __syncthreads();                                                          \
  }

  for (int io = 0; io < KI; io += 2) {
    GSTEP(io, 0, 1)
    GSTEP(io + 1, 1, 0)
  }
#undef GSTEP
}

// Pair K-split reduction through LDS (aliases the staging buffers — safe:
// last GSTEP ends with a barrier after all LDS reads have drained).
// Each wave ships the half of its columns its partner will finalize, then
// adds the partner's contribution into the half it keeps (nt in [2h, 2h+2)).
__device__ __forceinline__ void pair_reduce(floatx4 acc[4][4], Smem& sm,
                                            int pair, int half, int lr, int q) {
  const int oh = half ^ 1;
#pragma unroll
  for (int mt = 0; mt < 4; mt++)
#pragma unroll
    for (int j = 0; j < 2; j++) {
      const int nt = oh * 2 + j;
#pragma unroll
      for (int r = 0; r < 4; r++)
        sm.red[pair][oh][(mt * 16 + q * 4 + r) * RW + j * 16 + lr] =
            acc[mt][nt][r];
    }
  __syncthreads();
#pragma unroll
  for (int mt = 0; mt < 4; mt++)
#pragma unroll
    for (int j = 0; j < 2; j++) {
      const int nt = half * 2 + j;
#pragma unroll
      for (int r = 0; r < 4; r++)
        acc[mt][nt][r] +=
            sm.red[pair][half][(mt * 16 + q * 4 + r) * RW + j * 16 + lr];
    }
}

// GEMM1: Mb = bf16(A @ A), plus fused f32 row sums of A@A via atomics.
__global__ __launch_bounds__(512, 2) void gemm_aa(const u16* __restrict__ Ab,
                                                  const u16* __restrict__ Abt,
                                                  u16* __restrict__ Mb,
                                                  float* __restrict__ rsum) {
  __shared__ __align__(16) Smem sm;
  int bx, by;
  tile_xy(blockIdx.x, bx, by);
  const int row0 = by * TILE, col0 = bx * TILE;
  floatx4 acc[4][4];
  gemm_core(Ab, Abt, sm, row0, col0, acc);

  const int t = threadIdx.x, lane = t & 63, w = t >> 6;
  const int pair = w & 3, half = w >> 2;
  const int wr = (pair & 1) * 64, wc = (pair >> 1) * 64;
  const int lr = lane & 15, q = lane >> 4;
  pair_reduce(acc, sm, pair, half, lr, q);

#pragma unroll
  for (int mt = 0; mt < 4; mt++) {
#pragma unroll
    for (int r = 0; r < 4; r++) {
      const int rr = row0 + wr + mt * 16 + q * 4 + r;
      float s = 0.f;
#pragma unroll
      for (int j = 0; j < 2; j++) {
        const int nt = half * 2 + j;
        const float v = acc[mt][nt][r];
        s += v;
        Mb[(size_t)rr * N + col0 + wc + half * 32 + j * 16 + lr] = f2bf(v);
      }
      s += __shfl_xor(s, 1, 64);
      s += __shfl_xor(s, 2, 64);
      s += __shfl_xor(s, 4, 64);
      s += __shfl_xor(s, 8, 64);
      if (lr == 0) atomicAdd(&rsum[rr], s);  // 32-col partial of this row
    }
  }
}

// GEMM2 + fused norm epilogue: out = (8*(M@A) + 2*A) / (4*rowsum(M)+1)
__global__ __launch_bounds__(512, 2) void gemm_ma(const u16* __restrict__ Mb,
                                                  const u16* __restrict__ Abt,
                                                  const float* __restrict__ A,
                                                  const float* __restrict__ rsum,
                                                  float* __restrict__ out) {
  __shared__ __align__(16) Smem sm;
  int bx, by;
  tile_xy(blockIdx.x, bx, by);
  const int row0 = by * TILE, col0 = bx * TILE;
  floatx4 acc[4][4];
  gemm_core(Mb, Abt, sm, row0, col0, acc);

  const int t = threadIdx.x, lane = t & 63, w = t >> 6;
  const int pair = w & 3, half = w >> 2;
  const int wr = (pair & 1) * 64, wc = (pair >> 1) * 64;
  const int lr = lane & 15, q = lane >> 4;
  pair_reduce(acc, sm, pair, half, lr, q);

#pragma unroll
  for (int mt = 0; mt < 4; mt++) {
#pragma unroll
    for (int r = 0; r < 4; r++) {
      const int rr = row0 + wr + mt * 16 + q * 4 + r;
      float d = 4.f * rsum[rr] + 1.f;
      if (d <= 1e-10f) d = 1.f;
      const float rd = 1.f / d;
#pragma unroll
      for (int j = 0; j < 2; j++) {
        const int nt = half * 2 + j;
        const int cc = col0 + wc + half * 32 + j * 16 + lr;
        out[(size_t)rr * N + cc] =
            (8.f * acc[mt][nt][r] + 2.f * A[(size_t)rr * N + cc]) * rd;
      }
    }
  }
}

extern "C" void kernel_launch(void* const* d_in, const int* in_sizes, int n_in,
                              void* d_out, int out_size, void* d_ws, size_t ws_size,
                              hipStream_t stream) {
  const float* A = (const float*)d_in[0];
  // GTConv weights (d_in[1..3]) are irrelevant: softmax over a singleton axis
  // is identically 1, so each conv output is exactly 2*A.
  float* out = (float*)d_out;
  char* ws = (char*)d_ws;
  u16* Ab = (u16*)ws;                   // 8 MB bf16 A row-major
  u16* Abt = (u16*)(ws + NN * 2);       // 8 MB bf16 A transposed
  u16* Mb = (u16*)(ws + NN * 4);        // 8 MB bf16 M = A@A
  float* rsum = (float*)(ws + NN * 6);  // 8 KB f32 row sums of M (atomics)

  cast_tr<<<dim3(N / 32, N / 32), dim3(32, 8), 0, stream>>>(A, Ab, Abt, rsum);
  gemm_aa<<<dim3(256), 512, 0, stream>>>(Ab, Abt, Mb, rsum);
  gemm_ma<<<dim3(256), 512, 0, stream>>>(Mb, Abt, A, rsum, out);
}

// Round 2
// 134.921 us; speedup vs baseline: 4.6267x; 4.6267x over previous
//
#include <hip/hip_runtime.h>
#include <stdint.h>

#define N 2048
#define TILE 128
#define BK 64
#define KI (N / BK)      // 32 K-steps
#define LDSW 72          // u16 row stride: 144 B rows -> 16B-aligned, 2-way bank alias (free)
#define NN ((size_t)N * (size_t)N)

typedef unsigned short u16;
typedef __bf16 bf16x8 __attribute__((ext_vector_type(8)));
typedef unsigned short ushortx8 __attribute__((ext_vector_type(8)));
typedef float floatx4 __attribute__((ext_vector_type(4)));

static __device__ __forceinline__ u16 f2bf(float f) {
  unsigned int u = __builtin_bit_cast(unsigned int, f);
  return (u16)((u + 0x7fffu + ((u >> 16) & 1u)) >> 16);  // RNE, finite inputs
}
static __device__ __forceinline__ float bf2f(u16 h) {
  unsigned int u = ((unsigned int)h) << 16;
  return __builtin_bit_cast(float, u);
}

// ---------------------------------------------------------------------------
// cast + transpose: Ab[r][c] = bf16(A[r][c]); Abt[c][r] = bf16(A[r][c])
// ---------------------------------------------------------------------------
__global__ void cast_tr(const float* __restrict__ A, u16* __restrict__ Ab,
                        u16* __restrict__ Abt) {
  __shared__ float tile[32][33];
  const int tx = threadIdx.x, ty = threadIdx.y;
  const int c = blockIdx.x * 32 + tx;
#pragma unroll
  for (int i = 0; i < 4; i++) {
    const int r = blockIdx.y * 32 + ty + i * 8;
    const float v = A[(size_t)r * N + c];
    Ab[(size_t)r * N + c] = f2bf(v);
    tile[ty + i * 8][tx] = v;
  }
  __syncthreads();
  const int r2 = blockIdx.y * 32 + tx;
#pragma unroll
  for (int i = 0; i < 4; i++) {
    const int c2 = blockIdx.x * 32 + ty + i * 8;
    Abt[(size_t)c2 * N + r2] = f2bf(tile[tx][ty + i * 8]);
  }
}

// ---------------------------------------------------------------------------
// GEMM core: C = L[128 x N] * R[N x 128] (Rt stored [n][k]).
// Round-0 proven geometry: 512 threads = 8 waves; wave w owns a 64x32 output
// subtile (wr=(w>>2)*64, wc=(w&3)*32) -> acc[4][2] (32 VGPRs; round-1's
// acc[4][4] spilled: VGPR_Count=64, 1.1 GB scratch writes).
// Changes vs round 0 (the two register-pressure-independent wins):
//  - BK=64: 32 K-steps instead of 64.
//  - ONE barrier per step (publish buf[nxt], then __syncthreads):
//    all reads in step i target buf[cur]; writes in step i target buf[nxt];
//    the barrier at end of step i-1 orders prior reads of buf[nxt] before
//    this step's writes (round 1 ran this ordering and passed).
//  -> 32 full-drain barriers per GEMM instead of 128.
// Depth-2 register prefetch via plain global_load_dwordx4 (compiler emits
// precise per-wave vmcnt before the dependent ds_write).
// ---------------------------------------------------------------------------
__device__ __forceinline__ void gemm_core(const u16* __restrict__ L,
                                          const u16* __restrict__ Rt,
                                          floatx4 acc[4][2]) {
  __shared__ __align__(16) u16 As[2][TILE * LDSW];
  __shared__ __align__(16) u16 Bs[2][TILE * LDSW];

  const int t = threadIdx.x;             // 0..511
  const int row0 = blockIdx.y * TILE;
  const int col0 = blockIdx.x * TILE;

  // staging map: thread t covers row t>>2 (0..127), 32B chunk t&3 of each
  // 128-row x 64-col tile (two dwordx4 per array per tile)
  const int srow = t >> 2;
  const int sc = (t & 3) * 16;           // u16 offset
  const u16* gA = L + (size_t)(row0 + srow) * N + sc;
  const u16* gB = Rt + (size_t)(col0 + srow) * N + sc;
  const int woff = srow * LDSW + sc;     // LDS write offset (u16)

  const int lane = t & 63;
  const int w = t >> 6;                  // 0..7
  const int wr = (w >> 2) * 64;
  const int wc = (w & 3) * 32;
  const int lr = lane & 15;
  const int q = lane >> 4;
  const int abase = (wr + lr) * LDSW + q * 8;
  const int bbase = (wc + lr) * LDSW + q * 8;

#pragma unroll
  for (int i = 0; i < 4; i++)
#pragma unroll
    for (int j = 0; j < 2; j++) acc[i][j] = (floatx4){0.f, 0.f, 0.f, 0.f};

  ushortx8 sA[2][2], sB[2][2];           // [slot = tile&1][16B chunk]
  // prologue: tiles 0 and 1 into registers; publish tile 0
  sA[0][0] = *(const ushortx8*)(gA);
  sA[0][1] = *(const ushortx8*)(gA + 8);
  sB[0][0] = *(const ushortx8*)(gB);
  sB[0][1] = *(const ushortx8*)(gB + 8);
  sA[1][0] = *(const ushortx8*)(gA + BK);
  sA[1][1] = *(const ushortx8*)(gA + BK + 8);
  sB[1][0] = *(const ushortx8*)(gB + BK);
  sB[1][1] = *(const ushortx8*)(gB + BK + 8);
  *(ushortx8*)&As[0][woff] = sA[0][0];
  *(ushortx8*)&As[0][woff + 8] = sA[0][1];
  *(ushortx8*)&Bs[0][woff] = sB[0][0];
  *(ushortx8*)&Bs[0][woff + 8] = sB[0][1];
  __syncthreads();

  // step i: slot[cur] held tile i, already published at end of step i-1
  // (or prologue) -> refill it with tile i+2; compute on buf[cur];
  // publish tile i+1 (slot[nxt]) into buf[nxt]; one barrier.
#define GSTEP(i, cur, nxt)                                                    \
  {                                                                           \
    if ((i) + 2 < KI) {                                                       \
      sA[cur][0] = *(const ushortx8*)(gA + ((i) + 2) * BK);                   \
      sA[cur][1] = *(const ushortx8*)(gA + ((i) + 2) * BK + 8);               \
      sB[cur][0] = *(const ushortx8*)(gB + ((i) + 2) * BK);                   \
      sB[cur][1] = *(const ushortx8*)(gB + ((i) + 2) * BK + 8);               \
    }                                                                         \
    _Pragma("unroll") for (int kk = 0; kk < 2; kk++) {                        \
      bf16x8 af[4], bfr[2];                                                   \
      _Pragma("unroll") for (int mt = 0; mt < 4; mt++) af[mt] =               \
          __builtin_bit_cast(bf16x8,                                          \
              *(const ushortx8*)&As[cur][abase + kk * 32 + mt * 16 * LDSW]);  \
      _Pragma("unroll") for (int nt = 0; nt < 2; nt++) bfr[nt] =              \
          __builtin_bit_cast(bf16x8,                                          \
              *(const ushortx8*)&Bs[cur][bbase + kk * 32 + nt * 16 * LDSW]);  \
      _Pragma("unroll") for (int mt = 0; mt < 4; mt++)                        \
          _Pragma("unroll") for (int nt = 0; nt < 2; nt++) acc[mt][nt] =      \
              __builtin_amdgcn_mfma_f32_16x16x32_bf16(af[mt], bfr[nt],        \
                                                      acc[mt][nt], 0, 0, 0);  \
    }                                                                         \
    if ((i) + 1 < KI) {                                                       \
      *(ushortx8*)&As[nxt][woff] = sA[nxt][0];                                \
      *(ushortx8*)&As[nxt][woff + 8] = sA[nxt][1];                            \
      *(ushortx8*)&Bs[nxt][woff] = sB[nxt][0];                                \
      *(ushortx8*)&Bs[nxt][woff + 8] = sB[nxt][1];                            \
    }                                                                         \
    __syncthreads();                                                          \
  }

  for (int io = 0; io < KI; io += 2) {
    GSTEP(io, 0, 1)
    GSTEP(io + 1, 1, 0)
  }
#undef GSTEP
}

// GEMM1: Mb = bf16(A @ A)
__global__ __launch_bounds__(512, 2) void gemm_aa(const u16* __restrict__ Ab,
                                                  const u16* __restrict__ Abt,
                                                  u16* __restrict__ Mb) {
  floatx4 acc[4][2];
  gemm_core(Ab, Abt, acc);
  const int t = threadIdx.x;
  const int lane = t & 63, w = t >> 6;
  const int wr = (w >> 2) * 64, wc = (w & 3) * 32;
  const int lr = lane & 15, q = lane >> 4;
  const int row0 = blockIdx.y * TILE, col0 = blockIdx.x * TILE;
#pragma unroll
  for (int mt = 0; mt < 4; mt++)
#pragma unroll
    for (int r = 0; r < 4; r++) {
      const int rr = row0 + wr + mt * 16 + q * 4 + r;
#pragma unroll
      for (int nt = 0; nt < 2; nt++) {
        const int cc = col0 + wc + nt * 16 + lr;
        Mb[(size_t)rr * N + cc] = f2bf(acc[mt][nt][r]);
      }
    }
}

// rdeg[i] = 1 / (4*rowsum(M)_i + 1)   (with reference's <=1e-10 guard)
__global__ void rowsum_k(const u16* __restrict__ Mb, float* __restrict__ rdeg) {
  const int row = blockIdx.x;
  const int t = threadIdx.x;
  const ushortx8 v = *((const ushortx8*)(Mb + (size_t)row * N) + t);
  float s = 0.f;
#pragma unroll
  for (int j = 0; j < 8; j++) s += bf2f(v[j]);
#pragma unroll
  for (int off = 32; off > 0; off >>= 1) s += __shfl_down(s, off, 64);
  __shared__ float ws[4];
  if ((t & 63) == 0) ws[t >> 6] = s;
  __syncthreads();
  if (t == 0) {
    float d = 4.f * (ws[0] + ws[1] + ws[2] + ws[3]) + 1.f;
    if (d <= 1e-10f) d = 1.f;
    rdeg[row] = 1.f / d;
  }
}

// GEMM2 + fused norm epilogue: out = (8*(M@A) + 2*A) * rdeg[row]
__global__ __launch_bounds__(512, 2) void gemm_ma(const u16* __restrict__ Mb,
                                                  const u16* __restrict__ Abt,
                                                  const float* __restrict__ A,
                                                  const float* __restrict__ rdeg,
                                                  float* __restrict__ out) {
  floatx4 acc[4][2];
  gemm_core(Mb, Abt, acc);
  const int t = threadIdx.x;
  const int lane = t & 63, w = t >> 6;
  const int wr = (w >> 2) * 64, wc = (w & 3) * 32;
  const int lr = lane & 15, q = lane >> 4;
  const int row0 = blockIdx.y * TILE, col0 = blockIdx.x * TILE;
#pragma unroll
  for (int mt = 0; mt < 4; mt++)
#pragma unroll
    for (int r = 0; r < 4; r++) {
      const int rr = row0 + wr + mt * 16 + q * 4 + r;
      const float rd = rdeg[rr];
#pragma unroll
      for (int nt = 0; nt < 2; nt++) {
        const int cc = col0 + wc + nt * 16 + lr;
        out[(size_t)rr * N + cc] =
            (8.f * acc[mt][nt][r] + 2.f * A[(size_t)rr * N + cc]) * rd;
      }
    }
}

extern "C" void kernel_launch(void* const* d_in, const int* in_sizes, int n_in,
                              void* d_out, int out_size, void* d_ws, size_t ws_size,
                              hipStream_t stream) {
  const float* A = (const float*)d_in[0];
  // GTConv weights (d_in[1..3]) are irrelevant: softmax over a singleton axis
  // is identically 1, so each conv output is exactly 2*A.
  float* out = (float*)d_out;
  char* ws = (char*)d_ws;
  u16* Ab = (u16*)ws;                          // 8 MB bf16 A row-major
  u16* Abt = (u16*)(ws + NN * 2);              // 8 MB bf16 A transposed
  u16* Mb = (u16*)(ws + NN * 4);               // 8 MB bf16 M = A@A
  float* rdeg = (float*)(ws + NN * 6);         // 8 KB reciprocal degrees

  cast_tr<<<dim3(N / 32, N / 32), dim3(32, 8), 0, stream>>>(A, Ab, Abt);
  gemm_aa<<<dim3(N / TILE, N / TILE), 512, 0, stream>>>(Ab, Abt, Mb);
  rowsum_k<<<N, 256, 0, stream>>>(Mb, rdeg);
  gemm_ma<<<dim3(N / TILE, N / TILE), 512, 0, stream>>>(Mb, Abt, A, rdeg, out);
}